// Round 5
// baseline (231.997 us; speedup 1.0000x reference)
//
#include <hip/hip_runtime.h>
#include <hip/hip_bf16.h>

// BERT_SCL: loss = 0.9 * supcon(cls_emb, labels) + 0.1 * CE(pooled@W.T + b, labels)
// d_out[0] = loss, d_out[1..57344] = logits (8192 x 7, f32)
//
// e8 = fp8_e4m3(row-normalized cls * 1/sqrt(TEMP)); en = bf16 of the same.
// S_ij = e8_i . e8_j <= M = 1/TEMP -> fixed-max logsumexp. possum_i =
// en_i.T_{l_i} - ||en_i||^2 -> big kernel does ONLY exp-sums via MX-scaled
// fp8 MFMA (16x16x128, unit scales 0x7F). S symmetric -> upper triangle;
// off-diag tiles emit row AND col sums.
//
// Ledger: r2 single-address atomics; r3 supertile L2; r4 never force
// waves/EU; r5 <1blk/CU(4w) latency-bound; r6 staging-latency; r7 scaled
// MFMA + rotate swizzle; r8 node count weak lever (~160us residual fixed);
// r9 dbuf+raw-barrier 81->64.5; r10 direct-from-L2 FAILED 129 (strided
// frag gathers = request-rate bound); r11 ring3 @4waves/CU FAILED 82;
// r12 T1 XCD swizzle FETCH 25->16.5MB, k_scl 54.4, total 213.
// r13 (this): k_scl is LDS-PIPE-BOUND (per CU/kc-pair: LDS 2560cy vs MFMA
// 1107cy vs measured 2660). 64x64 wave tiles give 64 FLOP/LDS-read-B ->
// needs 118 B/cy > 85 achievable. Move to 256x256 block, 8 waves (512thr),
// wave-tile 128x64: 87 FLOP/B, stage/FLOP halves, barrier interval 2x
// (~3000cy covers HBM stragglers), 8 waves/CU = same TLP as champion.
// LDS 128KB dbuf (1 blk/CU). Triangle = 528 blocks (528%8==0 -> T1 ok),
// 4x4 supertiles. Target k_scl ~36-44us.

#define B_N 8192
#define D_K 768
#define NLAB 7
#define MBOUND 3.3333333333333335f /* 1/TEMP */
#define RTINV 1.8257418583505538f  /* 1/sqrt(TEMP) */

typedef float f32x4 __attribute__((ext_vector_type(4)));
typedef int i32x8 __attribute__((ext_vector_type(8)));

__device__ __forceinline__ void gl2lds16(const void* g, void* l) {
  __builtin_amdgcn_global_load_lds(
      (const __attribute__((address_space(1))) void*)g,
      (__attribute__((address_space(3))) void*)l, 16, 0, 0);
}

__device__ __forceinline__ float bf16u_to_f(unsigned short u) {
  return __uint_as_float(((unsigned int)u) << 16);
}

// exact fp8 e4m3fn -> f32 decode (fallback paths only)
__device__ __forceinline__ float dec8(unsigned int b) {
  unsigned int s = (b >> 7) & 1u, e = (b >> 3) & 15u, m = b & 7u;
  float fn = __uint_as_float((s << 31) | ((e + 120u) << 23) | (m << 20));
  float fs = (s ? -1.f : 1.f) * (float)m * 0.001953125f;
  return e ? fn : fs;
}

// ---- node 1: k_prep = zero accumulators + normalize -> {fp8, bf16} + logits + CE ----
template <int WBF>
__global__ __launch_bounds__(256) void k_prep(
    const float* __restrict__ cls, const float* __restrict__ pooled,
    const int* __restrict__ labels, const float* __restrict__ W,
    const float* __restrict__ bias, unsigned char* __restrict__ e8,
    unsigned short* __restrict__ en, float* __restrict__ logits_out,
    float* __restrict__ celoss, int* __restrict__ zr) {
  if (blockIdx.x == 0)
    for (int t = threadIdx.x; t < 9280; t += 256) zr[t] = 0;

  int wv = threadIdx.x >> 6, lane = threadIdx.x & 63;
  int row = blockIdx.x * 4 + wv;

  // --- normalize + quantize ---
  const float4* src = (const float4*)(cls + (size_t)row * D_K);
  float4 x[3];
  float ss = 0.f;
#pragma unroll
  for (int j = 0; j < 3; ++j) {
    x[j] = src[j * 64 + lane];
    ss += x[j].x * x[j].x + x[j].y * x[j].y + x[j].z * x[j].z + x[j].w * x[j].w;
  }
#pragma unroll
  for (int m = 1; m < 64; m <<= 1) ss += __shfl_xor(ss, m);
  float sc = rsqrtf(ss) * RTINV;
  int* d8 = (int*)(e8 + (size_t)row * D_K);
  ushort4* db = (ushort4*)(en + (size_t)row * D_K);
#pragma unroll
  for (int j = 0; j < 3; ++j) {
    int w32 = __builtin_amdgcn_cvt_pk_fp8_f32(x[j].x * sc, x[j].y * sc, 0, false);
    w32 = __builtin_amdgcn_cvt_pk_fp8_f32(x[j].z * sc, x[j].w * sc, w32, true);
    d8[j * 64 + lane] = w32;
    if (WBF) {
      const float* xv = reinterpret_cast<const float*>(&x[j]);
      ushort4 o;
      unsigned short* ov = reinterpret_cast<unsigned short*>(&o);
#pragma unroll
      for (int k = 0; k < 4; ++k) {
        __hip_bfloat16 h = __float2bfloat16(xv[k] * sc);
        ov[k] = *reinterpret_cast<unsigned short*>(&h);
      }
      db[j * 64 + lane] = o;
    }
  }

  // --- logits + CE ---
  const float4* p4 = (const float4*)(pooled + (size_t)row * D_K);
  float acc[NLAB];
#pragma unroll
  for (int c = 0; c < NLAB; ++c) acc[c] = 0.f;
#pragma unroll
  for (int j = 0; j < 3; ++j) {
    float4 xx = p4[j * 64 + lane];
#pragma unroll
    for (int c = 0; c < NLAB; ++c) {
      float4 w = ((const float4*)(W + c * D_K))[j * 64 + lane];
      acc[c] += xx.x * w.x + xx.y * w.y + xx.z * w.z + xx.w * w.w;
    }
  }
#pragma unroll
  for (int c = 0; c < NLAB; ++c)
#pragma unroll
    for (int m = 1; m < 64; m <<= 1) acc[c] += __shfl_xor(acc[c], m);
  if (lane == 0) {
    float l[NLAB], mx = -1e30f;
#pragma unroll
    for (int c = 0; c < NLAB; ++c) { l[c] = acc[c] + bias[c]; mx = fmaxf(mx, l[c]); }
    float se = 0.f;
#pragma unroll
    for (int c = 0; c < NLAB; ++c) se += __expf(l[c] - mx);
    float lse = mx + __logf(se);
    celoss[row] = lse - l[labels[row]];
    float* o = logits_out + (size_t)row * NLAB;
#pragma unroll
    for (int c = 0; c < NLAB; ++c) o[c] = l[c];
  }
}

// ---- node 2: class-sum stage A (direct stores) + hist ----
// 128 blocks: block g = (slab g>>1, dim-half g&1). Same partial layout
// (bitwise-identical sums). M=0: bf16 en; M=1: fp8 e8 (fallback).
template <int M>
__global__ __launch_bounds__(256) void k_classumA(
    const unsigned short* __restrict__ en, const unsigned char* __restrict__ e8,
    const int* __restrict__ labels, float* __restrict__ partial,
    int* __restrict__ hist) {
  int g = blockIdx.x, t = threadIdx.x;
  int slab = g >> 1, half = g & 1;
  int r0 = slab * 128;
  int dbase = half * 384;
  if (t < 96) {
    float acc[NLAB][4];
#pragma unroll
    for (int c = 0; c < NLAB; ++c)
#pragma unroll
      for (int k = 0; k < 4; ++k) acc[c][k] = 0.f;
    for (int r = 0; r < 128; r += 4) {
      int lab[4];
      float xv[4][4];
#pragma unroll
      for (int q = 0; q < 4; ++q) {
        int row = r0 + r + q;
        lab[q] = labels[row];
        if (M == 0) {
          ushort4 u = *(const ushort4*)(en + (size_t)row * D_K + dbase + t * 4);
          xv[q][0] = bf16u_to_f(u.x); xv[q][1] = bf16u_to_f(u.y);
          xv[q][2] = bf16u_to_f(u.z); xv[q][3] = bf16u_to_f(u.w);
        } else {
          uchar4 u = *(const uchar4*)(e8 + (size_t)row * D_K + dbase + t * 4);
          xv[q][0] = dec8(u.x); xv[q][1] = dec8(u.y);
          xv[q][2] = dec8(u.z); xv[q][3] = dec8(u.w);
        }
      }
#pragma unroll
      for (int q = 0; q < 4; ++q)
#pragma unroll
        for (int c = 0; c < NLAB; ++c) {
          bool m = (lab[q] == c);
          acc[c][0] += m ? xv[q][0] : 0.f;
          acc[c][1] += m ? xv[q][1] : 0.f;
          acc[c][2] += m ? xv[q][2] : 0.f;
          acc[c][3] += m ? xv[q][3] : 0.f;
        }
    }
    float* dst = partial + (size_t)slab * (NLAB * D_K) + dbase;
#pragma unroll
    for (int c = 0; c < NLAB; ++c) {
      float4 v = {acc[c][0], acc[c][1], acc[c][2], acc[c][3]};
      *(float4*)(dst + c * D_K + t * 4) = v;
    }
  } else if (t >= 192 && half == 0) {
    int lane = t - 192;
    int cnt[NLAB];
#pragma unroll
    for (int c = 0; c < NLAB; ++c) cnt[c] = 0;
#pragma unroll
    for (int q = 0; q < 2; ++q) {
      int lab = labels[r0 + q * 64 + lane];
#pragma unroll
      for (int c = 0; c < NLAB; ++c) cnt[c] += (lab == c);
    }
#pragma unroll
    for (int c = 0; c < NLAB; ++c)
#pragma unroll
      for (int m = 1; m < 64; m <<= 1) cnt[c] += __shfl_xor(cnt[c], m);
    if (lane == 0)
#pragma unroll
      for (int c = 0; c < NLAB; ++c) atomicAdd(&hist[c], cnt[c]);
  }
}

// ---- node 3: exp-sum S-tiles via MX-scaled fp8 MFMA (16x16x128), upper-tri ----
// 256x256 tiles, 8 waves (512 thr), wave-tile 128x64 (2 wr x 4 wc).
// Triangle over 32x32 tile grid = 528 blocks; blocks >= 528 run classumB.
// T1 XCD swizzle (528%8==0) + 4x4-tile supertiles keep per-XCD window
// ~1.5MB (L2-resident). LDS 128KB dbuf, 1 blk/CU but 8 waves = champion TLP;
// per kc: {sched_barrier; vmcnt(0); s_barrier; issue prefetch(kc+1); 4 held
// B-frags; stream 8 A-frags x 4 MFMA with setprio(1)}. Row-rotate swizzle on
// the GLOBAL source addr (DMA dest stays wave-uniform base + lane*16).
__global__ __launch_bounds__(512) void k_scl(const unsigned char* __restrict__ e8,
                                             float* __restrict__ rse,
                                             const float* __restrict__ partial,
                                             float* __restrict__ T) {
  if (blockIdx.x >= 528) {  // classumB role: T[idx] = sum_g partial[g][idx]
    int idx = (int)(blockIdx.x - 528) * 512 + threadIdx.x;
    if (idx < 5376) {
      float v = 0.f;
      for (int g = 0; g < 64; ++g) v += partial[(size_t)g * (NLAB * D_K) + idx];
      T[idx] = v;
    }
    return;
  }
  __shared__ __align__(16) unsigned char As[2][256 * 128];
  __shared__ __align__(16) unsigned char Bs[2][256 * 128];

  // T1: XCD-bijective swizzle (528 = 8 * 66 exactly)
  int orig = blockIdx.x;
  int rem = (orig & 7) * 66 + (orig >> 3);

  // supertile decode: 4x4-tile supertiles over the 32x32 triangle (8x8 STs)
  int SI = 0, SJ = 0;
  for (;;) {
    int sz = (SI == SJ) ? 10 : 16;
    if (rem < sz) break;
    rem -= sz;
    if (++SJ == 8) { ++SI; SJ = SI; }
  }
  int bi, bj;
  if (SI == SJ) {
    int r = 0, w = 4;
    while (rem >= w) { rem -= w; ++r; --w; }
    bi = SI * 4 + r;
    bj = SJ * 4 + r + rem;
  } else {
    bi = SI * 4 + (rem >> 2);
    bj = SJ * 4 + (rem & 3);
  }

  const int i0 = bi * 256, j0 = bj * 256;
  const int tid = threadIdx.x, wv = tid >> 6, lane = tid & 63;
  const int quad = lane >> 4, cix = lane & 15;
  const int rowTile = 128 * (wv >> 2), colTile = 64 * (wv & 3);

  // kc-invariant staging offsets (global source carries the swizzle)
  int aoff[4], boff[4], lbase[4];
#pragma unroll
  for (int it = 0; it < 4; ++it) {
    int s = it * 512 + tid;            // 16B slot in [0,2048)
    int r = s >> 3;                    // row 0..255
    int p = ((s & 7) - r) & 7;         // inverse of write swizzle
    aoff[it] = (i0 + r) * D_K + p * 16;
    boff[it] = (j0 + r) * D_K + p * 16;
    lbase[it] = (it * 512 + wv * 64) * 16;
  }

  f32x4 acc[8][4] = {};

  // prologue: prefetch kc=0 into buffer 0
#pragma unroll
  for (int it = 0; it < 4; ++it) {
    gl2lds16(e8 + (size_t)aoff[it], (char*)As[0] + lbase[it]);
    gl2lds16(e8 + (size_t)boff[it], (char*)Bs[0] + lbase[it]);
  }

#pragma unroll
  for (int kc = 0; kc < 6; ++kc) {
    const int cb = kc & 1;
    __builtin_amdgcn_sched_barrier(0);  // pin prior body (incl. MFMAs) above
    asm volatile("s_waitcnt vmcnt(0)" ::: "memory");  // prefetch(kc) landed
    __builtin_amdgcn_s_barrier();
    asm volatile("" ::: "memory");
    if (kc < 5) {  // prefetch kc+1 into other buffer; rides under compute
#pragma unroll
      for (int it = 0; it < 4; ++it) {
        gl2lds16(e8 + (size_t)(aoff[it] + (kc + 1) * 128), (char*)As[cb ^ 1] + lbase[it]);
        gl2lds16(e8 + (size_t)(boff[it] + (kc + 1) * 128), (char*)Bs[cb ^ 1] + lbase[it]);
      }
    }
    asm volatile("" ::: "memory");
    // hold 4 B-frags; stream A over 8 mt (1 live A frag)
    i32x8 bF[4];
#pragma unroll
    for (int nt = 0; nt < 4; ++nt) {
      int r = colTile + 16 * nt + cix;
      const char* base = (const char*)Bs[cb] + r * 128;
      int4 lo = *(const int4*)(base + (((quad * 2 + 0) + r) & 7) * 16);
      int4 hi = *(const int4*)(base + (((quad * 2 + 1) + r) & 7) * 16);
      bF[nt][0] = lo.x; bF[nt][1] = lo.y; bF[nt][2] = lo.z; bF[nt][3] = lo.w;
      bF[nt][4] = hi.x; bF[nt][5] = hi.y; bF[nt][6] = hi.z; bF[nt][7] = hi.w;
    }
    __builtin_amdgcn_s_setprio(1);  // T5: favor MFMA-cluster waves
#pragma unroll
    for (int mt = 0; mt < 8; ++mt) {
      int r = rowTile + 16 * mt + cix;
      const char* base = (const char*)As[cb] + r * 128;
      int4 lo = *(const int4*)(base + (((quad * 2 + 0) + r) & 7) * 16);
      int4 hi = *(const int4*)(base + (((quad * 2 + 1) + r) & 7) * 16);
      i32x8 aF;
      aF[0] = lo.x; aF[1] = lo.y; aF[2] = lo.z; aF[3] = lo.w;
      aF[4] = hi.x; aF[5] = hi.y; aF[6] = hi.z; aF[7] = hi.w;
#pragma unroll
      for (int nt = 0; nt < 4; ++nt)
        acc[mt][nt] = __builtin_amdgcn_mfma_scale_f32_16x16x128_f8f6f4(
            aF, bF[nt], acc[mt][nt], 0, 0, 0, 127, 0, 127);  // fp8 fmt, scale=1.0
    }
    __builtin_amdgcn_s_setprio(0);
  }

  // ---- epilogue: exp-sums only (16x16 C/D: col=lane&15, row=quad*4+rg) ----
  if (bi != bj) {
    float ce_col[4] = {0.f, 0.f, 0.f, 0.f};
#pragma unroll
    for (int mt = 0; mt < 8; ++mt) {
      int rowbase = i0 + rowTile + 16 * mt + quad * 4;
      float rs_e[4] = {0.f, 0.f, 0.f, 0.f};
#pragma unroll
      for (int nt = 0; nt < 4; ++nt) {
#pragma unroll
        for (int rg = 0; rg < 4; ++rg) {
          float e = __expf(acc[mt][nt][rg] - MBOUND);
          rs_e[rg] += e;
          ce_col[nt] += e;
        }
      }
#pragma unroll
      for (int rg = 0; rg < 4; ++rg)
#pragma unroll
        for (int m = 1; m <= 8; m <<= 1) rs_e[rg] += __shfl_xor(rs_e[rg], m);
      if (cix == 0)
#pragma unroll
        for (int rg = 0; rg < 4; ++rg) atomicAdd(&rse[rowbase + rg], rs_e[rg]);
    }
#pragma unroll
    for (int nt = 0; nt < 4; ++nt) {
      ce_col[nt] += __shfl_xor(ce_col[nt], 16);
      ce_col[nt] += __shfl_xor(ce_col[nt], 32);
    }
    if (quad == 0)
#pragma unroll
      for (int nt = 0; nt < 4; ++nt)
        atomicAdd(&rse[j0 + colTile + 16 * nt + cix], ce_col[nt]);
  } else {
#pragma unroll
    for (int mt = 0; mt < 8; ++mt) {
      int rowbase = i0 + rowTile + 16 * mt + quad * 4;
      float rs_e[4] = {0.f, 0.f, 0.f, 0.f};
#pragma unroll
      for (int nt = 0; nt < 4; ++nt) {
        int gcol = j0 + colTile + 16 * nt + cix;
#pragma unroll
        for (int rg = 0; rg < 4; ++rg) {
          bool dg = (rowbase + rg) == gcol;
          rs_e[rg] += dg ? 0.f : __expf(acc[mt][nt][rg] - MBOUND);
        }
      }
#pragma unroll
      for (int rg = 0; rg < 4; ++rg)
#pragma unroll
        for (int m = 1; m <= 8; m <<= 1) rs_e[rg] += __shfl_xor(rs_e[rg], m);
      if (cix == 0)
#pragma unroll
        for (int rg = 0; rg < 4; ++rg) atomicAdd(&rse[rowbase + rg], rs_e[rg]);
    }
  }
}

// ---- node 4: per-row combine + last-block final reduce (parallel) ----
template <int M>
__global__ __launch_bounds__(256) void k_rowfinal(
    const float* __restrict__ rse, const unsigned short* __restrict__ en,
    const unsigned char* __restrict__ e8, const float* __restrict__ T,
    const int* __restrict__ labels, const int* __restrict__ hist,
    const float* __restrict__ celoss, float* __restrict__ contrP,
    int* __restrict__ done_count, float* __restrict__ out) {
  __shared__ float part[4];
  __shared__ int is_last;
  int wv = threadIdx.x >> 6, lane = threadIdx.x & 63;
  int row = blockIdx.x * 4 + wv;
  int l = labels[row];
  const float4* t4 = (const float4*)(T + (size_t)l * D_K);
  float pd = 0.f, sd = 0.f;
#pragma unroll
  for (int j = 0; j < 3; ++j) {
    float a0, a1, a2, a3;
    if (M == 0) {
      ushort4 u = ((const ushort4*)(en + (size_t)row * D_K))[j * 64 + lane];
      a0 = bf16u_to_f(u.x); a1 = bf16u_to_f(u.y);
      a2 = bf16u_to_f(u.z); a3 = bf16u_to_f(u.w);
    } else {
      uint u = ((const uint*)(e8 + (size_t)row * D_K))[j * 64 + lane];
      a0 = dec8(u & 0xff); a1 = dec8((u >> 8) & 0xff);
      a2 = dec8((u >> 16) & 0xff); a3 = dec8(u >> 24);
    }
    float4 t = t4[j * 64 + lane];
    pd += a0 * t.x + a1 * t.y + a2 * t.z + a3 * t.w;
    sd += a0 * a0 + a1 * a1 + a2 * a2 + a3 * a3;
  }
#pragma unroll
  for (int m = 1; m < 64; m <<= 1) {
    pd += __shfl_xor(pd, m);
    sd += __shfl_xor(sd, m);
  }
  if (lane == 0) {
    int ni = hist[l] - 1;
    float per = 0.f;
    if (ni > 0) per = MBOUND + __logf(rse[row]) - (pd - sd) / (float)ni;
    part[wv] = 0.9f * per + (0.1f / (float)B_N) * celoss[row];
  }
  __syncthreads();
  if (threadIdx.x == 0) {
    float v = part[0] + part[1] + part[2] + part[3];
    atomicAdd(&contrP[(blockIdx.x & 63) * 16], v);
    __threadfence();
    int n = atomicAdd(done_count, 1);
    is_last = (n == (int)gridDim.x - 1) ? 1 : 0;
  }
  __syncthreads();
  if (is_last && threadIdx.x < 64) {
    float s = __hip_atomic_load(&contrP[threadIdx.x * 16], __ATOMIC_RELAXED,
                                __HIP_MEMORY_SCOPE_AGENT);
#pragma unroll
    for (int m = 1; m < 64; m <<= 1) s += __shfl_xor(s, m);
    if (threadIdx.x == 0) out[0] = s;
  }
}

extern "C" void kernel_launch(void* const* d_in, const int* in_sizes, int n_in,
                              void* d_out, int out_size, void* d_ws, size_t ws_size,
                              hipStream_t stream) {
  const float* cls    = (const float*)d_in[0];
  const float* pooled = (const float*)d_in[1];
  const int*   labels = (const int*)d_in[2];
  const float* W      = (const float*)d_in[3];
  const float* bias   = (const float*)d_in[4];
  float* out = (float*)d_out;

  char* ws = (char*)d_ws;
  unsigned char* e8 = (unsigned char*)ws;          // 6291456 B
  const size_t EN_B = (size_t)B_N * D_K * 2;       // 12582912
  const size_t E8_B = (size_t)B_N * D_K;           // 6291456
  size_t need_big = E8_B + EN_B + 98304 + 64 * (size_t)(NLAB * D_K) * 4;
  bool big = ws_size >= need_big;                  // 20348928 B
  unsigned short* en = (unsigned short*)(ws + E8_B);
  size_t off = big ? (E8_B + EN_B) : E8_B;
  float* rse     = (float*)(ws + off);             // +0      (32768) [zeroed]
  int*   hist    = (int*)(ws + off + 32768);       // +32768  (128)   [zeroed]
  int*   done    = (int*)(ws + off + 32896);       // +32896  (128)   [zeroed]
  float* contrP  = (float*)(ws + off + 33024);     // +33024  (4096)  [zeroed]
  float* T       = (float*)(ws + off + 37120);     // +37120  (21504, fully written)
  float* celoss  = (float*)(ws + off + 58624);     // +58624  (32768, fully written)
  float* partial = (float*)(ws + off + 98304);     // +98304  (1376256, fully written)
  int*   zr      = (int*)(ws + off);               // 9280 ints = rse..contrP

  if (big)
    k_prep<1><<<B_N / 4, 256, 0, stream>>>(cls, pooled, labels, W, bias, e8, en,
                                           out + 1, celoss, zr);
  else
    k_prep<0><<<B_N / 4, 256, 0, stream>>>(cls, pooled, labels, W, bias, e8, en,
                                           out + 1, celoss, zr);
  if (big)
    k_classumA<0><<<128, 256, 0, stream>>>(en, e8, labels, partial, hist);
  else
    k_classumA<1><<<128, 256, 0, stream>>>(en, e8, labels, partial, hist);
  k_scl<<<539, 512, 0, stream>>>(e8, rse, partial, T);  // 528 tiles + 11 classumB
  if (big)
    k_rowfinal<0><<<B_N / 4, 256, 0, stream>>>(rse, en, e8, T, labels, hist,
                                               celoss, contrP, done, out);
  else
    k_rowfinal<1><<<B_N / 4, 256, 0, stream>>>(rse, en, e8, T, labels, hist,
                                               celoss, contrP, done, out);
}

// Round 6
// 231.176 us; speedup vs baseline: 1.0036x; 1.0036x over previous
//
#include <hip/hip_runtime.h>
#include <hip/hip_bf16.h>

// BERT_SCL: loss = 0.9 * supcon(cls_emb, labels) + 0.1 * CE(pooled@W.T + b, labels)
// d_out[0] = loss, d_out[1..57344] = logits (8192 x 7, f32)
//
// e8 = fp8_e4m3(row-normalized cls * 1/sqrt(TEMP)); en = bf16 of the same.
// S_ij = e8_i . e8_j <= M = 1/TEMP -> fixed-max logsumexp. possum_i =
// en_i.T_{l_i} - ||en_i||^2 -> big kernel does ONLY exp-sums via MX-scaled
// fp8 MFMA (16x16x128, unit scales 0x7F). S symmetric -> upper triangle;
// off-diag tiles emit row AND col sums.
//
// Ledger: r2 single-address atomics; r3 supertile L2; r4 never force
// waves/EU; r5 <1blk/CU(4w) latency-bound; r6 staging-latency; r7 scaled
// MFMA + rotate swizzle; r8 node count weak lever (~155us residual fixed,
// only k_scl deltas move the total); r9 dbuf+raw-barrier 81->64.5;
// r10 direct-from-L2 FAILED 129 (strided frag gathers = request-rate
// bound); r11 ring3 @4waves/CU FAILED 82; r12 T1 XCD swizzle FETCH
// 25->16.5MB, k_scl 54.4 = AT THE LDS-PIPE CEILING (192KB/kc-pair / 85B/cy
// + conflicts ~= 2770cy ~= measured 2660); r13 256^2-tile FAILED 67.7 via
// ACC SPILL, not concept: __launch_bounds__(512) w/o min-waves capped VGPR
// at 128 < acc's 128+62 -> scratch (WRITE +15.5MB, FETCH +5.8MB).
// r14 (this): r13 + __launch_bounds__(512, 1) ONLY (VGPR budget 512, need
// ~195, still 2 waves/SIMD = 8 waves/CU). Isolates the spill variable.
// 256^2 raises FLOP/LDS-byte 43.7->65.6 (LDS-bound regime) -> predict
// k_scl ~30-38us, WRITE back to ~10.4MB, VGPR ~200. If VGPR/WRITE fix but
// dur >= 55: 1-blk/CU coupling is the cost -> revert to r12 for good.

#define B_N 8192
#define D_K 768
#define NLAB 7
#define MBOUND 3.3333333333333335f /* 1/TEMP */
#define RTINV 1.8257418583505538f  /* 1/sqrt(TEMP) */

typedef float f32x4 __attribute__((ext_vector_type(4)));
typedef int i32x8 __attribute__((ext_vector_type(8)));

__device__ __forceinline__ void gl2lds16(const void* g, void* l) {
  __builtin_amdgcn_global_load_lds(
      (const __attribute__((address_space(1))) void*)g,
      (__attribute__((address_space(3))) void*)l, 16, 0, 0);
}

__device__ __forceinline__ float bf16u_to_f(unsigned short u) {
  return __uint_as_float(((unsigned int)u) << 16);
}

// exact fp8 e4m3fn -> f32 decode (fallback paths only)
__device__ __forceinline__ float dec8(unsigned int b) {
  unsigned int s = (b >> 7) & 1u, e = (b >> 3) & 15u, m = b & 7u;
  float fn = __uint_as_float((s << 31) | ((e + 120u) << 23) | (m << 20));
  float fs = (s ? -1.f : 1.f) * (float)m * 0.001953125f;
  return e ? fn : fs;
}

// ---- node 1: k_prep = zero accumulators + normalize -> {fp8, bf16} + logits + CE ----
template <int WBF>
__global__ __launch_bounds__(256) void k_prep(
    const float* __restrict__ cls, const float* __restrict__ pooled,
    const int* __restrict__ labels, const float* __restrict__ W,
    const float* __restrict__ bias, unsigned char* __restrict__ e8,
    unsigned short* __restrict__ en, float* __restrict__ logits_out,
    float* __restrict__ celoss, int* __restrict__ zr) {
  if (blockIdx.x == 0)
    for (int t = threadIdx.x; t < 9280; t += 256) zr[t] = 0;

  int wv = threadIdx.x >> 6, lane = threadIdx.x & 63;
  int row = blockIdx.x * 4 + wv;

  // --- normalize + quantize ---
  const float4* src = (const float4*)(cls + (size_t)row * D_K);
  float4 x[3];
  float ss = 0.f;
#pragma unroll
  for (int j = 0; j < 3; ++j) {
    x[j] = src[j * 64 + lane];
    ss += x[j].x * x[j].x + x[j].y * x[j].y + x[j].z * x[j].z + x[j].w * x[j].w;
  }
#pragma unroll
  for (int m = 1; m < 64; m <<= 1) ss += __shfl_xor(ss, m);
  float sc = rsqrtf(ss) * RTINV;
  int* d8 = (int*)(e8 + (size_t)row * D_K);
  ushort4* db = (ushort4*)(en + (size_t)row * D_K);
#pragma unroll
  for (int j = 0; j < 3; ++j) {
    int w32 = __builtin_amdgcn_cvt_pk_fp8_f32(x[j].x * sc, x[j].y * sc, 0, false);
    w32 = __builtin_amdgcn_cvt_pk_fp8_f32(x[j].z * sc, x[j].w * sc, w32, true);
    d8[j * 64 + lane] = w32;
    if (WBF) {
      const float* xv = reinterpret_cast<const float*>(&x[j]);
      ushort4 o;
      unsigned short* ov = reinterpret_cast<unsigned short*>(&o);
#pragma unroll
      for (int k = 0; k < 4; ++k) {
        __hip_bfloat16 h = __float2bfloat16(xv[k] * sc);
        ov[k] = *reinterpret_cast<unsigned short*>(&h);
      }
      db[j * 64 + lane] = o;
    }
  }

  // --- logits + CE ---
  const float4* p4 = (const float4*)(pooled + (size_t)row * D_K);
  float acc[NLAB];
#pragma unroll
  for (int c = 0; c < NLAB; ++c) acc[c] = 0.f;
#pragma unroll
  for (int j = 0; j < 3; ++j) {
    float4 xx = p4[j * 64 + lane];
#pragma unroll
    for (int c = 0; c < NLAB; ++c) {
      float4 w = ((const float4*)(W + c * D_K))[j * 64 + lane];
      acc[c] += xx.x * w.x + xx.y * w.y + xx.z * w.z + xx.w * w.w;
    }
  }
#pragma unroll
  for (int c = 0; c < NLAB; ++c)
#pragma unroll
    for (int m = 1; m < 64; m <<= 1) acc[c] += __shfl_xor(acc[c], m);
  if (lane == 0) {
    float l[NLAB], mx = -1e30f;
#pragma unroll
    for (int c = 0; c < NLAB; ++c) { l[c] = acc[c] + bias[c]; mx = fmaxf(mx, l[c]); }
    float se = 0.f;
#pragma unroll
    for (int c = 0; c < NLAB; ++c) se += __expf(l[c] - mx);
    float lse = mx + __logf(se);
    celoss[row] = lse - l[labels[row]];
    float* o = logits_out + (size_t)row * NLAB;
#pragma unroll
    for (int c = 0; c < NLAB; ++c) o[c] = l[c];
  }
}

// ---- node 2: class-sum stage A (direct stores) + hist ----
// 128 blocks: block g = (slab g>>1, dim-half g&1). Same partial layout
// (bitwise-identical sums). M=0: bf16 en; M=1: fp8 e8 (fallback).
template <int M>
__global__ __launch_bounds__(256) void k_classumA(
    const unsigned short* __restrict__ en, const unsigned char* __restrict__ e8,
    const int* __restrict__ labels, float* __restrict__ partial,
    int* __restrict__ hist) {
  int g = blockIdx.x, t = threadIdx.x;
  int slab = g >> 1, half = g & 1;
  int r0 = slab * 128;
  int dbase = half * 384;
  if (t < 96) {
    float acc[NLAB][4];
#pragma unroll
    for (int c = 0; c < NLAB; ++c)
#pragma unroll
      for (int k = 0; k < 4; ++k) acc[c][k] = 0.f;
    for (int r = 0; r < 128; r += 4) {
      int lab[4];
      float xv[4][4];
#pragma unroll
      for (int q = 0; q < 4; ++q) {
        int row = r0 + r + q;
        lab[q] = labels[row];
        if (M == 0) {
          ushort4 u = *(const ushort4*)(en + (size_t)row * D_K + dbase + t * 4);
          xv[q][0] = bf16u_to_f(u.x); xv[q][1] = bf16u_to_f(u.y);
          xv[q][2] = bf16u_to_f(u.z); xv[q][3] = bf16u_to_f(u.w);
        } else {
          uchar4 u = *(const uchar4*)(e8 + (size_t)row * D_K + dbase + t * 4);
          xv[q][0] = dec8(u.x); xv[q][1] = dec8(u.y);
          xv[q][2] = dec8(u.z); xv[q][3] = dec8(u.w);
        }
      }
#pragma unroll
      for (int q = 0; q < 4; ++q)
#pragma unroll
        for (int c = 0; c < NLAB; ++c) {
          bool m = (lab[q] == c);
          acc[c][0] += m ? xv[q][0] : 0.f;
          acc[c][1] += m ? xv[q][1] : 0.f;
          acc[c][2] += m ? xv[q][2] : 0.f;
          acc[c][3] += m ? xv[q][3] : 0.f;
        }
    }
    float* dst = partial + (size_t)slab * (NLAB * D_K) + dbase;
#pragma unroll
    for (int c = 0; c < NLAB; ++c) {
      float4 v = {acc[c][0], acc[c][1], acc[c][2], acc[c][3]};
      *(float4*)(dst + c * D_K + t * 4) = v;
    }
  } else if (t >= 192 && half == 0) {
    int lane = t - 192;
    int cnt[NLAB];
#pragma unroll
    for (int c = 0; c < NLAB; ++c) cnt[c] = 0;
#pragma unroll
    for (int q = 0; q < 2; ++q) {
      int lab = labels[r0 + q * 64 + lane];
#pragma unroll
      for (int c = 0; c < NLAB; ++c) cnt[c] += (lab == c);
    }
#pragma unroll
    for (int c = 0; c < NLAB; ++c)
#pragma unroll
      for (int m = 1; m < 64; m <<= 1) cnt[c] += __shfl_xor(cnt[c], m);
    if (lane == 0)
#pragma unroll
      for (int c = 0; c < NLAB; ++c) atomicAdd(&hist[c], cnt[c]);
  }
}

// ---- node 3: exp-sum S-tiles via MX-scaled fp8 MFMA (16x16x128), upper-tri ----
// 256x256 tiles, 8 waves (512 thr), wave-tile 128x64 (2 wr x 4 wc).
// Triangle over 32x32 tile grid = 528 blocks; blocks >= 528 run classumB.
// T1 XCD swizzle (528%8==0) + 4x4-tile supertiles keep per-XCD window
// ~1.5MB (L2-resident). LDS 128KB dbuf, 1 blk/CU, 8 waves (2/SIMD).
// __launch_bounds__(512,1): VGPR budget 512 (need ~195; acc alone is 128)
// -- WITHOUT the ",1" hipcc caps at 128 and spills acc to scratch (r13).
// Per kc: {sched_barrier; vmcnt(0); s_barrier; issue prefetch(kc+1); 4 held
// B-frags; stream 8 A-frags x 4 MFMA with setprio(1)}. Row-rotate swizzle on
// the GLOBAL source addr (DMA dest stays wave-uniform base + lane*16).
__global__ __launch_bounds__(512, 1) void k_scl(const unsigned char* __restrict__ e8,
                                                float* __restrict__ rse,
                                                const float* __restrict__ partial,
                                                float* __restrict__ T) {
  if (blockIdx.x >= 528) {  // classumB role: T[idx] = sum_g partial[g][idx]
    int idx = (int)(blockIdx.x - 528) * 512 + threadIdx.x;
    if (idx < 5376) {
      float v = 0.f;
      for (int g = 0; g < 64; ++g) v += partial[(size_t)g * (NLAB * D_K) + idx];
      T[idx] = v;
    }
    return;
  }
  __shared__ __align__(16) unsigned char As[2][256 * 128];
  __shared__ __align__(16) unsigned char Bs[2][256 * 128];

  // T1: XCD-bijective swizzle (528 = 8 * 66 exactly)
  int orig = blockIdx.x;
  int rem = (orig & 7) * 66 + (orig >> 3);

  // supertile decode: 4x4-tile supertiles over the 32x32 triangle (8x8 STs)
  int SI = 0, SJ = 0;
  for (;;) {
    int sz = (SI == SJ) ? 10 : 16;
    if (rem < sz) break;
    rem -= sz;
    if (++SJ == 8) { ++SI; SJ = SI; }
  }
  int bi, bj;
  if (SI == SJ) {
    int r = 0, w = 4;
    while (rem >= w) { rem -= w; ++r; --w; }
    bi = SI * 4 + r;
    bj = SJ * 4 + r + rem;
  } else {
    bi = SI * 4 + (rem >> 2);
    bj = SJ * 4 + (rem & 3);
  }

  const int i0 = bi * 256, j0 = bj * 256;
  const int tid = threadIdx.x, wv = tid >> 6, lane = tid & 63;
  const int quad = lane >> 4, cix = lane & 15;
  const int rowTile = 128 * (wv >> 2), colTile = 64 * (wv & 3);

  // kc-invariant staging offsets (global source carries the swizzle)
  int aoff[4], boff[4], lbase[4];
#pragma unroll
  for (int it = 0; it < 4; ++it) {
    int s = it * 512 + tid;            // 16B slot in [0,2048)
    int r = s >> 3;                    // row 0..255
    int p = ((s & 7) - r) & 7;         // inverse of write swizzle
    aoff[it] = (i0 + r) * D_K + p * 16;
    boff[it] = (j0 + r) * D_K + p * 16;
    lbase[it] = (it * 512 + wv * 64) * 16;
  }

  f32x4 acc[8][4] = {};

  // prologue: prefetch kc=0 into buffer 0
#pragma unroll
  for (int it = 0; it < 4; ++it) {
    gl2lds16(e8 + (size_t)aoff[it], (char*)As[0] + lbase[it]);
    gl2lds16(e8 + (size_t)boff[it], (char*)Bs[0] + lbase[it]);
  }

#pragma unroll
  for (int kc = 0; kc < 6; ++kc) {
    const int cb = kc & 1;
    __builtin_amdgcn_sched_barrier(0);  // pin prior body (incl. MFMAs) above
    asm volatile("s_waitcnt vmcnt(0)" ::: "memory");  // prefetch(kc) landed
    __builtin_amdgcn_s_barrier();
    asm volatile("" ::: "memory");
    if (kc < 5) {  // prefetch kc+1 into other buffer; rides under compute
#pragma unroll
      for (int it = 0; it < 4; ++it) {
        gl2lds16(e8 + (size_t)(aoff[it] + (kc + 1) * 128), (char*)As[cb ^ 1] + lbase[it]);
        gl2lds16(e8 + (size_t)(boff[it] + (kc + 1) * 128), (char*)Bs[cb ^ 1] + lbase[it]);
      }
    }
    asm volatile("" ::: "memory");
    // hold 4 B-frags; stream A over 8 mt (1 live A frag)
    i32x8 bF[4];
#pragma unroll
    for (int nt = 0; nt < 4; ++nt) {
      int r = colTile + 16 * nt + cix;
      const char* base = (const char*)Bs[cb] + r * 128;
      int4 lo = *(const int4*)(base + (((quad * 2 + 0) + r) & 7) * 16);
      int4 hi = *(const int4*)(base + (((quad * 2 + 1) + r) & 7) * 16);
      bF[nt][0] = lo.x; bF[nt][1] = lo.y; bF[nt][2] = lo.z; bF[nt][3] = lo.w;
      bF[nt][4] = hi.x; bF[nt][5] = hi.y; bF[nt][6] = hi.z; bF[nt][7] = hi.w;
    }
    __builtin_amdgcn_s_setprio(1);  // T5: favor MFMA-cluster waves
#pragma unroll
    for (int mt = 0; mt < 8; ++mt) {
      int r = rowTile + 16 * mt + cix;
      const char* base = (const char*)As[cb] + r * 128;
      int4 lo = *(const int4*)(base + (((quad * 2 + 0) + r) & 7) * 16);
      int4 hi = *(const int4*)(base + (((quad * 2 + 1) + r) & 7) * 16);
      i32x8 aF;
      aF[0] = lo.x; aF[1] = lo.y; aF[2] = lo.z; aF[3] = lo.w;
      aF[4] = hi.x; aF[5] = hi.y; aF[6] = hi.z; aF[7] = hi.w;
#pragma unroll
      for (int nt = 0; nt < 4; ++nt)
        acc[mt][nt] = __builtin_amdgcn_mfma_scale_f32_16x16x128_f8f6f4(
            aF, bF[nt], acc[mt][nt], 0, 0, 0, 127, 0, 127);  // fp8 fmt, scale=1.0
    }
    __builtin_amdgcn_s_setprio(0);
  }

  // ---- epilogue: exp-sums only (16x16 C/D: col=lane&15, row=quad*4+rg) ----
  if (bi != bj) {
    float ce_col[4] = {0.f, 0.f, 0.f, 0.f};
#pragma unroll
    for (int mt = 0; mt < 8; ++mt) {
      int rowbase = i0 + rowTile + 16 * mt + quad * 4;
      float rs_e[4] = {0.f, 0.f, 0.f, 0.f};
#pragma unroll
      for (int nt = 0; nt < 4; ++nt) {
#pragma unroll
        for (int rg = 0; rg < 4; ++rg) {
          float e = __expf(acc[mt][nt][rg] - MBOUND);
          rs_e[rg] += e;
          ce_col[nt] += e;
        }
      }
#pragma unroll
      for (int rg = 0; rg < 4; ++rg)
#pragma unroll
        for (int m = 1; m <= 8; m <<= 1) rs_e[rg] += __shfl_xor(rs_e[rg], m);
      if (cix == 0)
#pragma unroll
        for (int rg = 0; rg < 4; ++rg) atomicAdd(&rse[rowbase + rg], rs_e[rg]);
    }
#pragma unroll
    for (int nt = 0; nt < 4; ++nt) {
      ce_col[nt] += __shfl_xor(ce_col[nt], 16);
      ce_col[nt] += __shfl_xor(ce_col[nt], 32);
    }
    if (quad == 0)
#pragma unroll
      for (int nt = 0; nt < 4; ++nt)
        atomicAdd(&rse[j0 + colTile + 16 * nt + cix], ce_col[nt]);
  } else {
#pragma unroll
    for (int mt = 0; mt < 8; ++mt) {
      int rowbase = i0 + rowTile + 16 * mt + quad * 4;
      float rs_e[4] = {0.f, 0.f, 0.f, 0.f};
#pragma unroll
      for (int nt = 0; nt < 4; ++nt) {
        int gcol = j0 + colTile + 16 * nt + cix;
#pragma unroll
        for (int rg = 0; rg < 4; ++rg) {
          bool dg = (rowbase + rg) == gcol;
          rs_e[rg] += dg ? 0.f : __expf(acc[mt][nt][rg] - MBOUND);
        }
      }
#pragma unroll
      for (int rg = 0; rg < 4; ++rg)
#pragma unroll
        for (int m = 1; m <= 8; m <<= 1) rs_e[rg] += __shfl_xor(rs_e[rg], m);
      if (cix == 0)
#pragma unroll
        for (int rg = 0; rg < 4; ++rg) atomicAdd(&rse[rowbase + rg], rs_e[rg]);
    }
  }
}

// ---- node 4: per-row combine + last-block final reduce (parallel) ----
template <int M>
__global__ __launch_bounds__(256) void k_rowfinal(
    const float* __restrict__ rse, const unsigned short* __restrict__ en,
    const unsigned char* __restrict__ e8, const float* __restrict__ T,
    const int* __restrict__ labels, const int* __restrict__ hist,
    const float* __restrict__ celoss, float* __restrict__ contrP,
    int* __restrict__ done_count, float* __restrict__ out) {
  __shared__ float part[4];
  __shared__ int is_last;
  int wv = threadIdx.x >> 6, lane = threadIdx.x & 63;
  int row = blockIdx.x * 4 + wv;
  int l = labels[row];
  const float4* t4 = (const float4*)(T + (size_t)l * D_K);
  float pd = 0.f, sd = 0.f;
#pragma unroll
  for (int j = 0; j < 3; ++j) {
    float a0, a1, a2, a3;
    if (M == 0) {
      ushort4 u = ((const ushort4*)(en + (size_t)row * D_K))[j * 64 + lane];
      a0 = bf16u_to_f(u.x); a1 = bf16u_to_f(u.y);
      a2 = bf16u_to_f(u.z); a3 = bf16u_to_f(u.w);
    } else {
      uint u = ((const uint*)(e8 + (size_t)row * D_K))[j * 64 + lane];
      a0 = dec8(u & 0xff); a1 = dec8((u >> 8) & 0xff);
      a2 = dec8((u >> 16) & 0xff); a3 = dec8(u >> 24);
    }
    float4 t = t4[j * 64 + lane];
    pd += a0 * t.x + a1 * t.y + a2 * t.z + a3 * t.w;
    sd += a0 * a0 + a1 * a1 + a2 * a2 + a3 * a3;
  }
#pragma unroll
  for (int m = 1; m < 64; m <<= 1) {
    pd += __shfl_xor(pd, m);
    sd += __shfl_xor(sd, m);
  }
  if (lane == 0) {
    int ni = hist[l] - 1;
    float per = 0.f;
    if (ni > 0) per = MBOUND + __logf(rse[row]) - (pd - sd) / (float)ni;
    part[wv] = 0.9f * per + (0.1f / (float)B_N) * celoss[row];
  }
  __syncthreads();
  if (threadIdx.x == 0) {
    float v = part[0] + part[1] + part[2] + part[3];
    atomicAdd(&contrP[(blockIdx.x & 63) * 16], v);
    __threadfence();
    int n = atomicAdd(done_count, 1);
    is_last = (n == (int)gridDim.x - 1) ? 1 : 0;
  }
  __syncthreads();
  if (is_last && threadIdx.x < 64) {
    float s = __hip_atomic_load(&contrP[threadIdx.x * 16], __ATOMIC_RELAXED,
                                __HIP_MEMORY_SCOPE_AGENT);
#pragma unroll
    for (int m = 1; m < 64; m <<= 1) s += __shfl_xor(s, m);
    if (threadIdx.x == 0) out[0] = s;
  }
}

extern "C" void kernel_launch(void* const* d_in, const int* in_sizes, int n_in,
                              void* d_out, int out_size, void* d_ws, size_t ws_size,
                              hipStream_t stream) {
  const float* cls    = (const float*)d_in[0];
  const float* pooled = (const float*)d_in[1];
  const int*   labels = (const int*)d_in[2];
  const float* W      = (const float*)d_in[3];
  const float* bias   = (const float*)d_in[4];
  float* out = (float*)d_out;

  char* ws = (char*)d_ws;
  unsigned char* e8 = (unsigned char*)ws;          // 6291456 B
  const size_t EN_B = (size_t)B_N * D_K * 2;       // 12582912
  const size_t E8_B = (size_t)B_N * D_K;           // 6291456
  size_t need_big = E8_B + EN_B + 98304 + 64 * (size_t)(NLAB * D_K) * 4;
  bool big = ws_size >= need_big;                  // 20348928 B
  unsigned short* en = (unsigned short*)(ws + E8_B);
  size_t off = big ? (E8_B + EN_B) : E8_B;
  float* rse     = (float*)(ws + off);             // +0      (32768) [zeroed]
  int*   hist    = (int*)(ws + off + 32768);       // +32768  (128)   [zeroed]
  int*   done    = (int*)(ws + off + 32896);       // +32896  (128)   [zeroed]
  float* contrP  = (float*)(ws + off + 33024);     // +33024  (4096)  [zeroed]
  float* T       = (float*)(ws + off + 37120);     // +37120  (21504, fully written)
  float* celoss  = (float*)(ws + off + 58624);     // +58624  (32768, fully written)
  float* partial = (float*)(ws + off + 98304);     // +98304  (1376256, fully written)
  int*   zr      = (int*)(ws + off);               // 9280 ints = rse..contrP

  if (big)
    k_prep<1><<<B_N / 4, 256, 0, stream>>>(cls, pooled, labels, W, bias, e8, en,
                                           out + 1, celoss, zr);
  else
    k_prep<0><<<B_N / 4, 256, 0, stream>>>(cls, pooled, labels, W, bias, e8, en,
                                           out + 1, celoss, zr);
  if (big)
    k_classumA<0><<<128, 256, 0, stream>>>(en, e8, labels, partial, hist);
  else
    k_classumA<1><<<128, 256, 0, stream>>>(en, e8, labels, partial, hist);
  k_scl<<<539, 512, 0, stream>>>(e8, rse, partial, T);  // 528 tiles + 11 classumB
  if (big)
    k_rowfinal<0><<<B_N / 4, 256, 0, stream>>>(rse, en, e8, T, labels, hist,
                                               celoss, contrP, done, out);
  else
    k_rowfinal<1><<<B_N / 4, 256, 0, stream>>>(rse, en, e8, T, labels, hist,
                                               celoss, contrP, done, out);
}

// Round 7
// 217.176 us; speedup vs baseline: 1.0682x; 1.0645x over previous
//
#include <hip/hip_runtime.h>
#include <hip/hip_bf16.h>

// BERT_SCL: loss = 0.9 * supcon(cls_emb, labels) + 0.1 * CE(pooled@W.T + b, labels)
// d_out[0] = loss, d_out[1..57344] = logits (8192 x 7, f32)
//
// e8 = fp8_e4m3(row-normalized cls * 1/sqrt(TEMP)) stored FRAGMENT-TILED:
//   byte (row, k) -> ((row/16)*6 + k/128)*2048 + (((k%128)/32)*16 + row%16)*32 + k%32
// so one MFMA fragment (16 rows x 32B of k) = 2KB CONTIGUOUS, lane l at l*32.
// en = bf16 of the normalized rows (row-major, feeds classumA/rowfinal).
// S_ij <= M = 1/TEMP -> fixed-max exp-sums via MX-scaled fp8 MFMA
// (16x16x128, unit scales 0x7F). S symmetric -> upper triangle (2080 tiles);
// off-diag tiles emit row AND col sums.
//
// Ledger: r2 single-address atomics; r3 supertile L2; r4 never force
// waves/EU; r5 <1blk/CU(4w) latency-bound; r6 staging-latency; r7 scaled
// MFMA + rotate swizzle; r8 node count weak lever (~159us residual fixed);
// r9 dbuf 81->64.5; r10 direct-from-L2 FAILED 129 -- because ROW-MAJOR
// frag gathers stride 768B = request-rate bound; r11 ring3@4waves FAILED;
// r12 T1 XCD swizzle -> k_scl 54.4 = AT the LDS-pipe ceiling (192KB/CU-kc
// / 85B/cy + conflicts ~ 2770cy = measured); r13/r14 256^2 FAILED twice:
// compiler pins VGPR=128 (occupancy step) -> acc[8][4] spills (WRITE
// +15.5MB scratch), launch_bounds(512,1) ignored -> 128x64 wave tiles are
// register-vetoed on this compiler.
// r15 (this): kill the LDS pipe instead of feeding it -- PRE-TILE e8 in
// k_prep so fragments are contiguous 2KB bursts; k_scl reads frags DIRECT
// from L2 (fixes r10's stride problem at the layout level). No LDS, no
// barriers, no DMA, no conflicts; full 6-kc unroll (96 loads / 96 MFMA),
// compiler-counted vmcnt; VGPR ~120 -> 16 waves/CU (2x champion TLP).
// L1 catches wave-pair frag reuse (panel 16KB < 32KB L1). Keep T1 XCD
// swizzle + 8x8 supertiles (window ~1.6MB, L2-fit). Fallback (small-ws)
// classumA<1>/rowfinal<1> read e8 via the same tiled index map.

#define B_N 8192
#define D_K 768
#define NLAB 7
#define MBOUND 3.3333333333333335f /* 1/TEMP */
#define RTINV 1.8257418583505538f  /* 1/sqrt(TEMP) */

typedef float f32x4 __attribute__((ext_vector_type(4)));
typedef int i32x8 __attribute__((ext_vector_type(8)));

__device__ __forceinline__ float bf16u_to_f(unsigned short u) {
  return __uint_as_float(((unsigned int)u) << 16);
}

// exact fp8 e4m3fn -> f32 decode (fallback paths only)
__device__ __forceinline__ float dec8(unsigned int b) {
  unsigned int s = (b >> 7) & 1u, e = (b >> 3) & 15u, m = b & 7u;
  float fn = __uint_as_float((s << 31) | ((e + 120u) << 23) | (m << 20));
  float fs = (s ? -1.f : 1.f) * (float)m * 0.001953125f;
  return e ? fn : fs;
}

// tiled e8 byte offset for (row, k4) where k4 is a byte index in [0,768)
__device__ __forceinline__ size_t e8t_off(int row, int k4) {
  int kblk = k4 >> 7, rem = k4 & 127;
  int quad = rem >> 5, off = rem & 31;
  return (size_t)((row >> 4) * 6 + kblk) * 2048 +
         (size_t)((quad * 16 + (row & 15)) * 32 + off);
}

// ---- node 1: k_prep = zero accumulators + normalize -> {fp8-tiled, bf16} + logits + CE ----
template <int WBF>
__global__ __launch_bounds__(256) void k_prep(
    const float* __restrict__ cls, const float* __restrict__ pooled,
    const int* __restrict__ labels, const float* __restrict__ W,
    const float* __restrict__ bias, unsigned char* __restrict__ e8,
    unsigned short* __restrict__ en, float* __restrict__ logits_out,
    float* __restrict__ celoss, int* __restrict__ zr) {
  if (blockIdx.x == 0)
    for (int t = threadIdx.x; t < 9280; t += 256) zr[t] = 0;

  int wv = threadIdx.x >> 6, lane = threadIdx.x & 63;
  int row = blockIdx.x * 4 + wv;

  // --- normalize + quantize ---
  const float4* src = (const float4*)(cls + (size_t)row * D_K);
  float4 x[3];
  float ss = 0.f;
#pragma unroll
  for (int j = 0; j < 3; ++j) {
    x[j] = src[j * 64 + lane];
    ss += x[j].x * x[j].x + x[j].y * x[j].y + x[j].z * x[j].z + x[j].w * x[j].w;
  }
#pragma unroll
  for (int m = 1; m < 64; m <<= 1) ss += __shfl_xor(ss, m);
  float sc = rsqrtf(ss) * RTINV;
  ushort4* db = (ushort4*)(en + (size_t)row * D_K);
#pragma unroll
  for (int j = 0; j < 3; ++j) {
    int w32 = __builtin_amdgcn_cvt_pk_fp8_f32(x[j].x * sc, x[j].y * sc, 0, false);
    w32 = __builtin_amdgcn_cvt_pk_fp8_f32(x[j].z * sc, x[j].w * sc, w32, true);
    // tiled write: this int covers k-bytes [(j*64+lane)*4, +4)
    *(int*)(e8 + e8t_off(row, (j * 64 + lane) * 4)) = w32;
    if (WBF) {
      const float* xv = reinterpret_cast<const float*>(&x[j]);
      ushort4 o;
      unsigned short* ov = reinterpret_cast<unsigned short*>(&o);
#pragma unroll
      for (int k = 0; k < 4; ++k) {
        __hip_bfloat16 h = __float2bfloat16(xv[k] * sc);
        ov[k] = *reinterpret_cast<unsigned short*>(&h);
      }
      db[j * 64 + lane] = o;
    }
  }

  // --- logits + CE ---
  const float4* p4 = (const float4*)(pooled + (size_t)row * D_K);
  float acc[NLAB];
#pragma unroll
  for (int c = 0; c < NLAB; ++c) acc[c] = 0.f;
#pragma unroll
  for (int j = 0; j < 3; ++j) {
    float4 xx = p4[j * 64 + lane];
#pragma unroll
    for (int c = 0; c < NLAB; ++c) {
      float4 w = ((const float4*)(W + c * D_K))[j * 64 + lane];
      acc[c] += xx.x * w.x + xx.y * w.y + xx.z * w.z + xx.w * w.w;
    }
  }
#pragma unroll
  for (int c = 0; c < NLAB; ++c)
#pragma unroll
    for (int m = 1; m < 64; m <<= 1) acc[c] += __shfl_xor(acc[c], m);
  if (lane == 0) {
    float l[NLAB], mx = -1e30f;
#pragma unroll
    for (int c = 0; c < NLAB; ++c) { l[c] = acc[c] + bias[c]; mx = fmaxf(mx, l[c]); }
    float se = 0.f;
#pragma unroll
    for (int c = 0; c < NLAB; ++c) se += __expf(l[c] - mx);
    float lse = mx + __logf(se);
    celoss[row] = lse - l[labels[row]];
    float* o = logits_out + (size_t)row * NLAB;
#pragma unroll
    for (int c = 0; c < NLAB; ++c) o[c] = l[c];
  }
}

// ---- node 2: class-sum stage A (direct stores) + hist ----
// 128 blocks: block g = (slab g>>1, dim-half g&1). Same partial layout
// (bitwise-identical sums). M=0: bf16 en (row-major); M=1: fp8 e8 (TILED).
template <int M>
__global__ __launch_bounds__(256) void k_classumA(
    const unsigned short* __restrict__ en, const unsigned char* __restrict__ e8,
    const int* __restrict__ labels, float* __restrict__ partial,
    int* __restrict__ hist) {
  int g = blockIdx.x, t = threadIdx.x;
  int slab = g >> 1, half = g & 1;
  int r0 = slab * 128;
  int dbase = half * 384;
  if (t < 96) {
    float acc[NLAB][4];
#pragma unroll
    for (int c = 0; c < NLAB; ++c)
#pragma unroll
      for (int k = 0; k < 4; ++k) acc[c][k] = 0.f;
    for (int r = 0; r < 128; r += 4) {
      int lab[4];
      float xv[4][4];
#pragma unroll
      for (int q = 0; q < 4; ++q) {
        int row = r0 + r + q;
        lab[q] = labels[row];
        if (M == 0) {
          ushort4 u = *(const ushort4*)(en + (size_t)row * D_K + dbase + t * 4);
          xv[q][0] = bf16u_to_f(u.x); xv[q][1] = bf16u_to_f(u.y);
          xv[q][2] = bf16u_to_f(u.z); xv[q][3] = bf16u_to_f(u.w);
        } else {
          uchar4 u = *(const uchar4*)(e8 + e8t_off(row, dbase + t * 4));
          xv[q][0] = dec8(u.x); xv[q][1] = dec8(u.y);
          xv[q][2] = dec8(u.z); xv[q][3] = dec8(u.w);
        }
      }
#pragma unroll
      for (int q = 0; q < 4; ++q)
#pragma unroll
        for (int c = 0; c < NLAB; ++c) {
          bool m = (lab[q] == c);
          acc[c][0] += m ? xv[q][0] : 0.f;
          acc[c][1] += m ? xv[q][1] : 0.f;
          acc[c][2] += m ? xv[q][2] : 0.f;
          acc[c][3] += m ? xv[q][3] : 0.f;
        }
    }
    float* dst = partial + (size_t)slab * (NLAB * D_K) + dbase;
#pragma unroll
    for (int c = 0; c < NLAB; ++c) {
      float4 v = {acc[c][0], acc[c][1], acc[c][2], acc[c][3]};
      *(float4*)(dst + c * D_K + t * 4) = v;
    }
  } else if (t >= 192 && half == 0) {
    int lane = t - 192;
    int cnt[NLAB];
#pragma unroll
    for (int c = 0; c < NLAB; ++c) cnt[c] = 0;
#pragma unroll
    for (int q = 0; q < 2; ++q) {
      int lab = labels[r0 + q * 64 + lane];
#pragma unroll
      for (int c = 0; c < NLAB; ++c) cnt[c] += (lab == c);
    }
#pragma unroll
    for (int c = 0; c < NLAB; ++c)
#pragma unroll
      for (int m = 1; m < 64; m <<= 1) cnt[c] += __shfl_xor(cnt[c], m);
    if (lane == 0)
#pragma unroll
      for (int c = 0; c < NLAB; ++c) atomicAdd(&hist[c], cnt[c]);
  }
}

// ---- node 3: exp-sum S-tiles via MX-scaled fp8 MFMA (16x16x128), upper-tri ----
// NO LDS. e8 is fragment-tiled: frag (rowblock rb, kchunk kc) = 2KB
// contiguous at (rb*6+kc)*2048, lane l holds bytes [l*32, l*32+32) = row
// (l&15), k-bytes (l>>4)*32.. of the chunk -- exactly the MFMA A/B operand
// layout (lane = quad*16+cix). Each wave loads its 8 frags/kc as coalesced
// dwordx4 pairs straight from L2; waves fully independent, compiler
// pipelines the unrolled 96-load/96-MFMA body with counted vmcnt.
// T1 XCD-bijective block swizzle + 8x8 supertiles keep the per-XCD window
// ~1.6MB (L2-resident). Blocks >= 2080 run class-sum stage B.
__global__ __launch_bounds__(256) void k_scl(const unsigned char* __restrict__ e8,
                                             float* __restrict__ rse,
                                             const float* __restrict__ partial,
                                             float* __restrict__ T) {
  if (blockIdx.x >= 2080) {  // classumB role: T[idx] = sum_g partial[g][idx]
    int idx = (int)(blockIdx.x - 2080) * 256 + threadIdx.x;  // < 5376
    float v = 0.f;
    for (int g = 0; g < 64; ++g) v += partial[(size_t)g * (NLAB * D_K) + idx];
    T[idx] = v;
    return;
  }

  // T1: XCD-bijective swizzle (2080 = 8 * 260 exactly)
  int orig = blockIdx.x;
  int rem = (orig & 7) * 260 + (orig >> 3);

  // supertile decode: 8x8-block supertiles over the triangle
  int BI = 0, BJ = 0;
  for (;;) {
    int sz = (BI == BJ) ? 36 : 64;
    if (rem < sz) break;
    rem -= sz;
    if (++BJ == 8) { ++BI; BJ = BI; }
  }
  int bi, bj;
  if (BI == BJ) {
    int r = 0, w = 8;
    while (rem >= w) { rem -= w; ++r; --w; }
    bi = BI * 8 + r;
    bj = BJ * 8 + r + rem;
  } else {
    bi = BI * 8 + (rem >> 3);
    bj = BJ * 8 + (rem & 7);
  }

  const int i0 = bi * 128, j0 = bj * 128;
  const int tid = threadIdx.x, wv = tid >> 6, lane = tid & 63;
  const int quad = lane >> 4, cix = lane & 15;
  const int rowTile = 64 * (wv >> 1), colTile = 64 * (wv & 1);

  // fragment base pointers: row-block (i0+rowTile)/16, lane offset lane*32
  const unsigned char* abase =
      e8 + (size_t)(((i0 + rowTile) >> 4) * 6) * 2048 + lane * 32;
  const unsigned char* bbase =
      e8 + (size_t)(((j0 + colTile) >> 4) * 6) * 2048 + lane * 32;

  f32x4 acc[4][4] = {};

#pragma unroll
  for (int kc = 0; kc < 6; ++kc) {
    i32x8 aF[4];
#pragma unroll
    for (int mt = 0; mt < 4; ++mt) {  // frag (rb+mt, kc): +mt*12288 + kc*2048
      const unsigned char* p = abase + mt * 12288 + kc * 2048;
      int4 lo = *(const int4*)p;
      int4 hi = *(const int4*)(p + 16);
      aF[mt][0] = lo.x; aF[mt][1] = lo.y; aF[mt][2] = lo.z; aF[mt][3] = lo.w;
      aF[mt][4] = hi.x; aF[mt][5] = hi.y; aF[mt][6] = hi.z; aF[mt][7] = hi.w;
    }
#pragma unroll
    for (int nt = 0; nt < 4; ++nt) {  // bF streamed: 1 live frag
      const unsigned char* p = bbase + nt * 12288 + kc * 2048;
      int4 lo = *(const int4*)p;
      int4 hi = *(const int4*)(p + 16);
      i32x8 bF;
      bF[0] = lo.x; bF[1] = lo.y; bF[2] = lo.z; bF[3] = lo.w;
      bF[4] = hi.x; bF[5] = hi.y; bF[6] = hi.z; bF[7] = hi.w;
#pragma unroll
      for (int mt = 0; mt < 4; ++mt)
        acc[mt][nt] = __builtin_amdgcn_mfma_scale_f32_16x16x128_f8f6f4(
            aF[mt], bF, acc[mt][nt], 0, 0, 0, 127, 0, 127);  // fp8 fmt, scale=1.0
    }
  }

  // ---- epilogue: exp-sums only (16x16 C/D: col=lane&15, row=quad*4+rg) ----
  if (bi != bj) {
    float ce_col[4] = {0.f, 0.f, 0.f, 0.f};
#pragma unroll
    for (int mt = 0; mt < 4; ++mt) {
      int rowbase = i0 + rowTile + 16 * mt + quad * 4;
      float rs_e[4] = {0.f, 0.f, 0.f, 0.f};
#pragma unroll
      for (int nt = 0; nt < 4; ++nt) {
#pragma unroll
        for (int rg = 0; rg < 4; ++rg) {
          float e = __expf(acc[mt][nt][rg] - MBOUND);
          rs_e[rg] += e;
          ce_col[nt] += e;
        }
      }
#pragma unroll
      for (int rg = 0; rg < 4; ++rg)
#pragma unroll
        for (int m = 1; m <= 8; m <<= 1) rs_e[rg] += __shfl_xor(rs_e[rg], m);
      if (cix == 0)
#pragma unroll
        for (int rg = 0; rg < 4; ++rg) atomicAdd(&rse[rowbase + rg], rs_e[rg]);
    }
#pragma unroll
    for (int nt = 0; nt < 4; ++nt) {
      ce_col[nt] += __shfl_xor(ce_col[nt], 16);
      ce_col[nt] += __shfl_xor(ce_col[nt], 32);
    }
    if (quad == 0)
#pragma unroll
      for (int nt = 0; nt < 4; ++nt)
        atomicAdd(&rse[j0 + colTile + 16 * nt + cix], ce_col[nt]);
  } else {
#pragma unroll
    for (int mt = 0; mt < 4; ++mt) {
      int rowbase = i0 + rowTile + 16 * mt + quad * 4;
      float rs_e[4] = {0.f, 0.f, 0.f, 0.f};
#pragma unroll
      for (int nt = 0; nt < 4; ++nt) {
        int gcol = j0 + colTile + 16 * nt + cix;
#pragma unroll
        for (int rg = 0; rg < 4; ++rg) {
          bool dg = (rowbase + rg) == gcol;
          rs_e[rg] += dg ? 0.f : __expf(acc[mt][nt][rg] - MBOUND);
        }
      }
#pragma unroll
      for (int rg = 0; rg < 4; ++rg)
#pragma unroll
        for (int m = 1; m <= 8; m <<= 1) rs_e[rg] += __shfl_xor(rs_e[rg], m);
      if (cix == 0)
#pragma unroll
        for (int rg = 0; rg < 4; ++rg) atomicAdd(&rse[rowbase + rg], rs_e[rg]);
    }
  }
}

// ---- node 4: per-row combine + last-block final reduce (parallel) ----
template <int M>
__global__ __launch_bounds__(256) void k_rowfinal(
    const float* __restrict__ rse, const unsigned short* __restrict__ en,
    const unsigned char* __restrict__ e8, const float* __restrict__ T,
    const int* __restrict__ labels, const int* __restrict__ hist,
    const float* __restrict__ celoss, float* __restrict__ contrP,
    int* __restrict__ done_count, float* __restrict__ out) {
  __shared__ float part[4];
  __shared__ int is_last;
  int wv = threadIdx.x >> 6, lane = threadIdx.x & 63;
  int row = blockIdx.x * 4 + wv;
  int l = labels[row];
  const float4* t4 = (const float4*)(T + (size_t)l * D_K);
  float pd = 0.f, sd = 0.f;
#pragma unroll
  for (int j = 0; j < 3; ++j) {
    float a0, a1, a2, a3;
    if (M == 0) {
      ushort4 u = ((const ushort4*)(en + (size_t)row * D_K))[j * 64 + lane];
      a0 = bf16u_to_f(u.x); a1 = bf16u_to_f(u.y);
      a2 = bf16u_to_f(u.z); a3 = bf16u_to_f(u.w);
    } else {
      uint u = *(const uint*)(e8 + e8t_off(row, (j * 64 + lane) * 4));
      a0 = dec8(u & 0xff); a1 = dec8((u >> 8) & 0xff);
      a2 = dec8((u >> 16) & 0xff); a3 = dec8(u >> 24);
    }
    float4 t = t4[j * 64 + lane];
    pd += a0 * t.x + a1 * t.y + a2 * t.z + a3 * t.w;
    sd += a0 * a0 + a1 * a1 + a2 * a2 + a3 * a3;
  }
#pragma unroll
  for (int m = 1; m < 64; m <<= 1) {
    pd += __shfl_xor(pd, m);
    sd += __shfl_xor(sd, m);
  }
  if (lane == 0) {
    int ni = hist[l] - 1;
    float per = 0.f;
    if (ni > 0) per = MBOUND + __logf(rse[row]) - (pd - sd) / (float)ni;
    part[wv] = 0.9f * per + (0.1f / (float)B_N) * celoss[row];
  }
  __syncthreads();
  if (threadIdx.x == 0) {
    float v = part[0] + part[1] + part[2] + part[3];
    atomicAdd(&contrP[(blockIdx.x & 63) * 16], v);
    __threadfence();
    int n = atomicAdd(done_count, 1);
    is_last = (n == (int)gridDim.x - 1) ? 1 : 0;
  }
  __syncthreads();
  if (is_last && threadIdx.x < 64) {
    float s = __hip_atomic_load(&contrP[threadIdx.x * 16], __ATOMIC_RELAXED,
                                __HIP_MEMORY_SCOPE_AGENT);
#pragma unroll
    for (int m = 1; m < 64; m <<= 1) s += __shfl_xor(s, m);
    if (threadIdx.x == 0) out[0] = s;
  }
}

extern "C" void kernel_launch(void* const* d_in, const int* in_sizes, int n_in,
                              void* d_out, int out_size, void* d_ws, size_t ws_size,
                              hipStream_t stream) {
  const float* cls    = (const float*)d_in[0];
  const float* pooled = (const float*)d_in[1];
  const int*   labels = (const int*)d_in[2];
  const float* W      = (const float*)d_in[3];
  const float* bias   = (const float*)d_in[4];
  float* out = (float*)d_out;

  char* ws = (char*)d_ws;
  unsigned char* e8 = (unsigned char*)ws;          // 6291456 B (fragment-tiled)
  const size_t EN_B = (size_t)B_N * D_K * 2;       // 12582912
  const size_t E8_B = (size_t)B_N * D_K;           // 6291456
  size_t need_big = E8_B + EN_B + 98304 + 64 * (size_t)(NLAB * D_K) * 4;
  bool big = ws_size >= need_big;                  // 20348928 B
  unsigned short* en = (unsigned short*)(ws + E8_B);
  size_t off = big ? (E8_B + EN_B) : E8_B;
  float* rse     = (float*)(ws + off);             // +0      (32768) [zeroed]
  int*   hist    = (int*)(ws + off + 32768);       // +32768  (128)   [zeroed]
  int*   done    = (int*)(ws + off + 32896);       // +32896  (128)   [zeroed]
  float* contrP  = (float*)(ws + off + 33024);     // +33024  (4096)  [zeroed]
  float* T       = (float*)(ws + off + 37120);     // +37120  (21504, fully written)
  float* celoss  = (float*)(ws + off + 58624);     // +58624  (32768, fully written)
  float* partial = (float*)(ws + off + 98304);     // +98304  (1376256, fully written)
  int*   zr      = (int*)(ws + off);               // 9280 ints = rse..contrP

  if (big)
    k_prep<1><<<B_N / 4, 256, 0, stream>>>(cls, pooled, labels, W, bias, e8, en,
                                           out + 1, celoss, zr);
  else
    k_prep<0><<<B_N / 4, 256, 0, stream>>>(cls, pooled, labels, W, bias, e8, en,
                                           out + 1, celoss, zr);
  if (big)
    k_classumA<0><<<128, 256, 0, stream>>>(en, e8, labels, partial, hist);
  else
    k_classumA<1><<<128, 256, 0, stream>>>(en, e8, labels, partial, hist);
  k_scl<<<2101, 256, 0, stream>>>(e8, rse, partial, T);  // +21 classumB blocks
  if (big)
    k_rowfinal<0><<<B_N / 4, 256, 0, stream>>>(rse, en, e8, T, labels, hist,
                                               celoss, contrP, done, out);
  else
    k_rowfinal<1><<<B_N / 4, 256, 0, stream>>>(rse, en, e8, T, labels, hist,
                                               celoss, contrP, done, out);
}